// Round 19
// baseline (4618.228 us; speedup 1.0000x reference)
//
#include <hip/hip_runtime.h>
#include <math.h>

#define BATCH 64
#define TT 256
#define IN_DIM 512
#define H 1024
#define SLOT 65536   // u32 per h slot (1024 j x 64 b)
#define XSLOT 32768  // u32 per x slot

typedef __attribute__((ext_vector_type(8))) _Float16 f16x8;
typedef __attribute__((ext_vector_type(4))) float f32x4;
typedef unsigned int u32;
typedef unsigned long long u64;
typedef __attribute__((ext_vector_type(4))) u32 u32x4;

#define MFMA16 __builtin_amdgcn_mfma_f32_16x16x32_f16
#define SCOPE_AGENT __HIP_MEMORY_SCOPE_AGENT

union FB { u32 u[4]; f16x8 v; };

__device__ __forceinline__ float sigm(float v) { return 1.f / (1.f + __expf(-v)); }
__device__ __forceinline__ float tanhf_(float v) {
    float e = __expf(-2.f * fabsf(v));
    float r = (1.f - e) / (1.f + e);
    return v < 0.f ? -r : r;
}
// B-side pack: stored pair (hi = f16(32u), lo = f16(32u - hi)); u = (hi+lo)/32
__device__ __forceinline__ u32 packu(float v) {
    float s = v * 32.f;
    _Float16 hi = (_Float16)s;
    _Float16 lo = (_Float16)(s - (float)hi);
    return (u32)__builtin_bit_cast(unsigned short, hi)
         | ((u32)__builtin_bit_cast(unsigned short, lo) << 16);
}
__device__ __forceinline__ void unpack8(const u64* r, f16x8& bh, f16x8& bl) {
    FB Hf, Lf;
#pragma unroll
    for (int i = 0; i < 4; ++i) {
        u32 p0 = (u32)r[i], p1 = (u32)(r[i] >> 32);
        Hf.u[i] = __builtin_amdgcn_perm(p1, p0, 0x05040100u);
        Lf.u[i] = __builtin_amdgcn_perm(p1, p0, 0x07060302u);
    }
    bh = Hf.v; bl = Lf.v;
}
// W-side split: hi = f16(64W), lo = f16(64W - hi).
// Products: hi_W*hi_B + hi_W*lo_B + lo_W*hi_B all at scale 2048*W*u -> one acc.
__device__ __forceinline__ void wsplit8(const float4& a0, const float4& a1, f16x8& hi, f16x8& lo) {
    float tmp[8] = {a0.x, a0.y, a0.z, a0.w, a1.x, a1.y, a1.z, a1.w};
#pragma unroll
    for (int e = 0; e < 8; ++e) {
        float s = tmp[e] * 64.f;
        _Float16 h_ = (_Float16)s;
        hi[e] = h_;
        lo[e] = (_Float16)(s - (float)h_);
    }
}
// 16B device-coherent writethrough store (cross-XCD visible). sc0 sc1 flags.
__device__ __forceinline__ void store16_wt(u32* addr, u32x4 v) {
    asm volatile("global_store_dwordx4 %0, %1, off sc0 sc1"
                 :: "v"((u64)(uintptr_t)addr), "v"(v) : "memory");
}

// ---------------------------------------------------------------------------
__global__ void zero_kernel(u32* __restrict__ p, int n) {
    int i = blockIdx.x * 256 + threadIdx.x;
    if (i < n) p[i] = 0u;
}

// ---------------------------------------------------------------------------
// x[b][t][k] fp32 -> xpack[t][(k>>3)*512 + b*8 + (k&7)] packed u32
__global__ __launch_bounds__(512) void xT_kernel(
    const float* __restrict__ x, u32* __restrict__ xpack) {
    const int tid = threadIdx.x, t = blockIdx.x;
    const int b = tid & 63, kq = tid >> 6;
#pragma unroll
    for (int kb = 0; kb < 8; ++kb) {
        int k = kb * 64 + kq * 8;
        const float* src = x + ((size_t)b * TT + t) * IN_DIM + k;
        float4 v0 = *(const float4*)src;
        float4 v1 = *(const float4*)(src + 4);
        u32 o[8] = {packu(v0.x), packu(v0.y), packu(v0.z), packu(v0.w),
                    packu(v1.x), packu(v1.y), packu(v1.z), packu(v1.w)};
        u32* dst = xpack + (size_t)t * XSLOT + (kb * 8 + kq) * 512 + b * 8;
        *(uint4*)dst = make_uint4(o[0], o[1], o[2], o[3]);
        *(uint4*)(dst + 4) = make_uint4(o[4], o[5], o[6], o[7]);
    }
}

// ---------------------------------------------------------------------------
// Fused staggered 2-layer recurrence body, phase-split (r14-verified sync
// structure). NEW (r18): per-block chunk-order rotation -- blocks walk the
// h/x broadcast cachelines in staggered order to de-serialize L3 bursts.
// Pure reordering of commutative accumulation; protocol unchanged.
template<int NC, int NCA, int KX, int XS, int DEP>
__device__ __forceinline__ void rec_body(
    const float* __restrict__ Wih, const float* __restrict__ Whh,
    const float* __restrict__ bias, const u32* __restrict__ xbuf,
    u32* hbuf, int* ownflags, int* depflags,
    float (*scr)[32][66], u32* hx, int gbid) {
    const int tid = threadIdx.x;
    const int l = tid & 63, w = tid >> 6;
    const int arow = l & 15, akg = l >> 4;
    const int eb = l;
    const int rotA = gbid & (NCA - 1);     // phase-A rotation (NCA = 2 or 4)
    const int rotB = gbid & 3;             // phase-B rotation (NC-NCA == 4)

    // ---- W fragments (scaled split f16), k-slice s = c*8+w
    f16x8 Ah[2][NC], Al[2][NC];
#pragma unroll
    for (int m = 0; m < 2; ++m) {
        const int rp = gbid * 32 + m * 16 + arow;
        const float* wihrow = Wih + (size_t)((rp & 3) * H + (rp >> 2)) * KX;
        const float* whhrow = Whh + (size_t)((rp & 3) * H + (rp >> 2)) * H;
#pragma unroll
        for (int c = 0; c < NC; ++c) {
            int g = (c * 8 + w) * 32 + akg * 8;
            const float* src = (g < KX) ? (wihrow + g) : (whhrow + (g - KX));
            float4 v0 = *(const float4*)src;
            float4 v1 = *(const float4*)(src + 4);
            wsplit8(v0, v1, Ah[m][c], Al[m][c]);
        }
    }
    // ---- PIN W fragments into AGPRs (verified r12: removed W re-stream)
#pragma unroll
    for (int m = 0; m < 2; ++m)
#pragma unroll
        for (int c = 0; c < NC; ++c)
            asm volatile("" : "+a"(Ah[m][c]), "+a"(Al[m][c]));

    // ---- per-chunk B offsets (in-slot u32 index); c<NCA -> x-source
    int boff[NC];
#pragma unroll
    for (int c = 0; c < NC; ++c) {
        int g0 = (c * 8 + w) * 32;
        int gl = (g0 >= KX) ? (g0 - KX) : g0;
        boff[c] = (gl >> 3) * 512 + akg * 512 + arow * 8;
    }
    // ---- bias (hoisted)
    float gbias[4];
#pragma unroll
    for (int g = 0; g < 4; ++g) {
        int rp = gbid * 32 + w * 4 + g;
        gbias[g] = bias[(rp & 3) * H + (rp >> 2)];
    }

    float cs = 0.f;

    for (int t = 0; t < TT; ++t) {
        f32x4 acc[2][4];
#pragma unroll
        for (int m = 0; m < 2; ++m)
#pragma unroll
            for (int ns = 0; ns < 4; ++ns) acc[m][ns] = (f32x4){0.f, 0.f, 0.f, 0.f};

        // ======== phase A: x / ys chunks (rotated order) ========
        if (DEP) {   // ys slot t+1 needs dep (layer0) flag >= t+1
            if (w == 0) {
                bool done = false;
                while (!done) {
                    int d0 = __hip_atomic_load(&depflags[l], __ATOMIC_RELAXED, SCOPE_AGENT);
                    int d1 = __hip_atomic_load(&depflags[l + 64], __ATOMIC_RELAXED, SCOPE_AGENT);
                    done = __all(((d0 < d1) ? d0 : d1) >= t + 1);
                    if (!done) __builtin_amdgcn_s_sleep(1);
                }
            }
            __builtin_amdgcn_sched_barrier(0);
            __syncthreads();
        }
        const u32* xb = xbuf + (size_t)(DEP ? t + 1 : t) * XS;
#pragma unroll
        for (int cc = 0; cc < NCA; ++cc) {
            const int c = (cc + rotA) & (NCA - 1);
            const u32* bp0 = xb + boff[c];
            u64 raw[4][4];
#pragma unroll
            for (int ns = 0; ns < 4; ++ns) {
                const u32* bp = bp0 + ns * 128;
                *(uint4*)&raw[ns][0] = *(const uint4*)bp;
                *(uint4*)&raw[ns][2] = *(const uint4*)(bp + 4);
            }
#pragma unroll
            for (int ns = 0; ns < 4; ++ns) {
                f16x8 bh, bl;
                unpack8(raw[ns], bh, bl);
#pragma unroll
                for (int m = 0; m < 2; ++m) {
                    acc[m][ns] = MFMA16(Ah[m][c], bh, acc[m][ns], 0, 0, 0);
                    acc[m][ns] = MFMA16(Ah[m][c], bl, acc[m][ns], 0, 0, 0);
                    acc[m][ns] = MFMA16(Al[m][c], bh, acc[m][ns], 0, 0, 0);
                }
            }
        }

        // ======== phase B: h chunks (own flag >= t; rotated order) ========
        if (w == 0) {
            bool done = false;
            while (!done) {
                int o0 = __hip_atomic_load(&ownflags[l], __ATOMIC_RELAXED, SCOPE_AGENT);
                int o1 = __hip_atomic_load(&ownflags[l + 64], __ATOMIC_RELAXED, SCOPE_AGENT);
                done = __all(((o0 < o1) ? o0 : o1) >= t);
                if (!done) __builtin_amdgcn_s_sleep(1);
            }
        }
        __builtin_amdgcn_sched_barrier(0);
        __syncthreads();

        const u32* hb = hbuf + (size_t)t * SLOT;
#pragma unroll
        for (int cc = 0; cc < NC - NCA; ++cc) {
            const int c = NCA + ((cc + rotB) & 3);
            const u32* bp0 = hb + boff[c];
            u64 raw[4][4];
#pragma unroll
            for (int ns = 0; ns < 4; ++ns) {
                const u32* bp = bp0 + ns * 128;
                *(uint4*)&raw[ns][0] = *(const uint4*)bp;
                *(uint4*)&raw[ns][2] = *(const uint4*)(bp + 4);
            }
#pragma unroll
            for (int ns = 0; ns < 4; ++ns) {
                f16x8 bh, bl;
                unpack8(raw[ns], bh, bl);
#pragma unroll
                for (int m = 0; m < 2; ++m) {
                    acc[m][ns] = MFMA16(Ah[m][c], bh, acc[m][ns], 0, 0, 0);
                    acc[m][ns] = MFMA16(Ah[m][c], bl, acc[m][ns], 0, 0, 0);
                    acc[m][ns] = MFMA16(Al[m][c], bh, acc[m][ns], 0, 0, 0);
                }
            }
        }

        // ---- partial-K reduce via LDS (stride 66: <=2-way conflicts)
#pragma unroll
        for (int m = 0; m < 2; ++m)
#pragma unroll
            for (int ns = 0; ns < 4; ++ns)
#pragma unroll
                for (int r = 0; r < 4; ++r)
                    scr[w][m * 16 + akg * 4 + r][ns * 16 + arow] = acc[m][ns][r];
        __syncthreads();

        // ---- epilogue: thread (unit=w, batch=eb)
        {
            float gg[4];
#pragma unroll
            for (int g = 0; g < 4; ++g) {
                int rl = w * 4 + g;
                float s = 0.f;
#pragma unroll
                for (int ww = 0; ww < 8; ++ww) s += scr[ww][rl][eb];
                gg[g] = s * (1.f / 2048.f) + gbias[g];
            }
            float is = sigm(gg[0]), fs = sigm(gg[1]), gt = tanhf_(gg[2]), os = sigm(gg[3]);
            cs = fs * cs + is * gt;
            float hnew = os * tanhf_(cs);
            hx[w * 72 + eb] = packu(hnew);
        }
        __syncthreads();

        // ---- dense vectorized coherent store: 128 x 16B -> slot t+1
        if (tid < 128) {
            int base = tid * 4;
            u32x4 v;
            v.x = hx[((base + 0) & 7) * 72 + ((base + 0) >> 3)];
            v.y = hx[((base + 1) & 7) * 72 + ((base + 1) >> 3)];
            v.z = hx[((base + 2) & 7) * 72 + ((base + 2) >> 3)];
            v.w = hx[((base + 3) & 7) * 72 + ((base + 3) >> 3)];
            store16_wt(hbuf + (size_t)(t + 1) * SLOT + gbid * 512 + base, v);
        }
        asm volatile("s_waitcnt vmcnt(0)" ::: "memory");
        __syncthreads();   // all stores drained before flag
        if (tid == 0)
            __hip_atomic_store(&ownflags[gbid], t + 1, __ATOMIC_RELEASE, SCOPE_AGENT);
    }
}

// ---------------------------------------------------------------------------
// 256 blocks x 512 thr, 1 block/CU. XCD affinity (bid%8 = XCD): layer 0 on
// XCDs 0-3 (x from xpack, K=1536), layer 1 on XCDs 4-7 (x from ys, K=2048),
// staggered one step behind.
__global__ __launch_bounds__(512)
__attribute__((amdgpu_waves_per_eu(2, 2)))
void rec_fused(
    const float* __restrict__ Wih0, const float* __restrict__ Whh0, const float* __restrict__ b0,
    const float* __restrict__ Wih1, const float* __restrict__ Whh1, const float* __restrict__ b1,
    const u32* __restrict__ xpack, u32* ys, u32* hs1, int* flags0, int* flags1) {
    __shared__ float scr[8][32][66];
    __shared__ u32 hx[8 * 72];
    const int bid = blockIdx.x;
    const int xcd = bid & 7;
    const int gbid = (bid >> 3) * 4 + (xcd & 3);
    if (xcd < 4)
        rec_body<6, 2, 512, XSLOT, 0>(Wih0, Whh0, b0, xpack, ys, flags0, nullptr, scr, hx, gbid);
    else
        rec_body<8, 4, 1024, SLOT, 1>(Wih1, Whh1, b1, ys, hs1, flags1, flags0, scr, hx, gbid);
}

// ---------------------------------------------------------------------------
// out[b][o] = sum_j h[j][b] * Wfc[o][j] + bfc[o]; h from hs1 slot 256
__global__ __launch_bounds__(256) void fc_kernel(
    const u32* __restrict__ hp, const float* __restrict__ Wfc,
    const float* __restrict__ bfc, float* __restrict__ out) {
    const int tid = threadIdx.x;
    const int b = tid & 63;
    const int o = blockIdx.x * 4 + (tid >> 6);
    const float* wr = Wfc + (size_t)o * H;
    float acc = 0.f;
    for (int jb = 0; jb < 128; ++jb) {
        const u64* bp = (const u64*)(hp + (size_t)jb * 512 + b * 8);
        u64 raw[4] = {bp[0], bp[1], bp[2], bp[3]};
        f16x8 vh, vl;
        unpack8(raw, vh, vl);
#pragma unroll
        for (int e = 0; e < 8; ++e) {
            float hv = ((float)vh[e] + (float)vl[e]) * (1.f / 32.f);
            acc += hv * wr[jb * 8 + e];
        }
    }
    out[(size_t)b * 512 + o] = acc + bfc[o];
}

// ---------------------------------------------------------------------------
extern "C" void kernel_launch(void* const* d_in, const int* in_sizes, int n_in,
                              void* d_out, int out_size, void* d_ws, size_t ws_size,
                              hipStream_t stream) {
    const float* x    = (const float*)d_in[0];
    const float* Wih0 = (const float*)d_in[1];
    const float* Whh0 = (const float*)d_in[2];
    const float* b0   = (const float*)d_in[3];
    const float* Wih1 = (const float*)d_in[4];
    const float* Whh1 = (const float*)d_in[5];
    const float* b1   = (const float*)d_in[6];
    const float* Wfc  = (const float*)d_in[7];
    const float* bfc  = (const float*)d_in[8];
    float* out = (float*)d_out;

    // ws (u32): ys 257*SLOT | hs1 257*SLOT | xpack 256*XSLOT | flags0 | +8KB | flags1
    char* p = (char*)d_ws;
    u32* ys     = (u32*)p; p += (size_t)257 * SLOT * 4;
    u32* hs1    = (u32*)p; p += (size_t)257 * SLOT * 4;
    u32* xpack  = (u32*)p; p += (size_t)256 * XSLOT * 4;
    int* flags0 = (int*)p; p += 8192;   // 8KB separation: different L3 sets
    int* flags1 = (int*)p;

    // zero slot-0 of ys/hs1 + both flag arrays (every launch)
    zero_kernel<<<SLOT / 256, 256, 0, stream>>>(ys, SLOT);
    zero_kernel<<<SLOT / 256, 256, 0, stream>>>(hs1, SLOT);
    zero_kernel<<<1, 256, 0, stream>>>((u32*)flags0, 128);
    zero_kernel<<<1, 256, 0, stream>>>((u32*)flags1, 128);

    xT_kernel<<<TT, 512, 0, stream>>>(x, xpack);

    rec_fused<<<256, 512, 0, stream>>>(
        Wih0, Whh0, b0, Wih1, Whh1, b1, xpack, ys, hs1, flags0, flags1);

    fc_kernel<<<128, 256, 0, stream>>>(hs1 + (size_t)256 * SLOT, Wfc, bfc, out);
}

// Round 21
// 3539.812 us; speedup vs baseline: 1.3047x; 1.3047x over previous
//
#include <hip/hip_runtime.h>
#include <math.h>

#define BATCH 64
#define TT 256
#define IN_DIM 512
#define H 1024
#define SLOT 65536   // u32 per h slot (1024 j x 64 b)
#define XSLOT 32768  // u32 per x slot

typedef __attribute__((ext_vector_type(8))) _Float16 f16x8;
typedef __attribute__((ext_vector_type(4))) float f32x4;
typedef unsigned int u32;
typedef unsigned long long u64;
typedef __attribute__((ext_vector_type(4))) u32 u32x4;

#define MFMA16 __builtin_amdgcn_mfma_f32_16x16x32_f16
#define SCOPE_AGENT __HIP_MEMORY_SCOPE_AGENT

union FB { u32 u[4]; f16x8 v; };

__device__ __forceinline__ float sigm(float v) { return 1.f / (1.f + __expf(-v)); }
__device__ __forceinline__ float tanhf_(float v) {
    float e = __expf(-2.f * fabsf(v));
    float r = (1.f - e) / (1.f + e);
    return v < 0.f ? -r : r;
}
// B-side pack: stored pair (hi = f16(32u), lo = f16(32u - hi)); u = (hi+lo)/32
__device__ __forceinline__ u32 packu(float v) {
    float s = v * 32.f;
    _Float16 hi = (_Float16)s;
    _Float16 lo = (_Float16)(s - (float)hi);
    return (u32)__builtin_bit_cast(unsigned short, hi)
         | ((u32)__builtin_bit_cast(unsigned short, lo) << 16);
}
__device__ __forceinline__ void unpack8(const u64* r, f16x8& bh, f16x8& bl) {
    FB Hf, Lf;
#pragma unroll
    for (int i = 0; i < 4; ++i) {
        u32 p0 = (u32)r[i], p1 = (u32)(r[i] >> 32);
        Hf.u[i] = __builtin_amdgcn_perm(p1, p0, 0x05040100u);
        Lf.u[i] = __builtin_amdgcn_perm(p1, p0, 0x07060302u);
    }
    bh = Hf.v; bl = Lf.v;
}
// W-side split: hi = f16(64W), lo = f16(64W - hi).
// Products: hi_W*hi_B + hi_W*lo_B + lo_W*hi_B all at scale 2048*W*u -> one acc.
__device__ __forceinline__ void wsplit8(const float4& a0, const float4& a1, f16x8& hi, f16x8& lo) {
    float tmp[8] = {a0.x, a0.y, a0.z, a0.w, a1.x, a1.y, a1.z, a1.w};
#pragma unroll
    for (int e = 0; e < 8; ++e) {
        float s = tmp[e] * 64.f;
        _Float16 h_ = (_Float16)s;
        hi[e] = h_;
        lo[e] = (_Float16)(s - (float)h_);
    }
}
// 16B device-coherent writethrough store (cross-XCD visible). sc0 sc1 flags.
__device__ __forceinline__ void store16_wt(u32* addr, u32x4 v) {
    asm volatile("global_store_dwordx4 %0, %1, off sc0 sc1"
                 :: "v"((u64)(uintptr_t)addr), "v"(v) : "memory");
}

// ---------------------------------------------------------------------------
__global__ void zero_kernel(u32* __restrict__ p, int n) {
    int i = blockIdx.x * 256 + threadIdx.x;
    if (i < n) p[i] = 0u;
}

// ---------------------------------------------------------------------------
// x[b][t][k] fp32 -> xpack[t][(k>>3)*512 + b*8 + (k&7)] packed u32
__global__ __launch_bounds__(512) void xT_kernel(
    const float* __restrict__ x, u32* __restrict__ xpack) {
    const int tid = threadIdx.x, t = blockIdx.x;
    const int b = tid & 63, kq = tid >> 6;
#pragma unroll
    for (int kb = 0; kb < 8; ++kb) {
        int k = kb * 64 + kq * 8;
        const float* src = x + ((size_t)b * TT + t) * IN_DIM + k;
        float4 v0 = *(const float4*)src;
        float4 v1 = *(const float4*)(src + 4);
        u32 o[8] = {packu(v0.x), packu(v0.y), packu(v0.z), packu(v0.w),
                    packu(v1.x), packu(v1.y), packu(v1.z), packu(v1.w)};
        u32* dst = xpack + (size_t)t * XSLOT + (kb * 8 + kq) * 512 + b * 8;
        *(uint4*)dst = make_uint4(o[0], o[1], o[2], o[3]);
        *(uint4*)(dst + 4) = make_uint4(o[4], o[5], o[6], o[7]);
    }
}

// ---------------------------------------------------------------------------
// Fused staggered 2-layer recurrence body, phase-split (verified sync
// structure: wave0 polls + barrier broadcast; tid<128 store; all-thread
// vmcnt drain; barrier; tid0 release flag -- the trailing barrier after
// store+flag is LOAD-BEARING, r15/r16/r19 bisect).
// Phase A (c < NCA): sources need no flag (L0 x) or only dep flag (L1 ys).
// Phase B (c >= NCA): h_prev, gated by own flag.
template<int NC, int NCA, int KX, int XS, int DEP>
__device__ __forceinline__ void rec_body(
    const float* __restrict__ Wih, const float* __restrict__ Whh,
    const float* __restrict__ bias, const u32* __restrict__ xbuf,
    u32* hbuf, int* ownflags, int* depflags,
    float (*scr)[32][66], u32* hx, int gbid) {
    const int tid = threadIdx.x;
    const int l = tid & 63, w = tid >> 6;
    const int arow = l & 15, akg = l >> 4;
    const int eb = l;

    // ---- W fragments (scaled split f16), k-slice s = c*8+w
    f16x8 Ah[2][NC], Al[2][NC];
#pragma unroll
    for (int m = 0; m < 2; ++m) {
        const int rp = gbid * 32 + m * 16 + arow;
        const float* wihrow = Wih + (size_t)((rp & 3) * H + (rp >> 2)) * KX;
        const float* whhrow = Whh + (size_t)((rp & 3) * H + (rp >> 2)) * H;
#pragma unroll
        for (int c = 0; c < NC; ++c) {
            int g = (c * 8 + w) * 32 + akg * 8;
            const float* src = (g < KX) ? (wihrow + g) : (whhrow + (g - KX));
            float4 v0 = *(const float4*)src;
            float4 v1 = *(const float4*)(src + 4);
            wsplit8(v0, v1, Ah[m][c], Al[m][c]);
        }
    }
    // ---- PIN W fragments into AGPRs (verified r12: removed W re-stream)
#pragma unroll
    for (int m = 0; m < 2; ++m)
#pragma unroll
        for (int c = 0; c < NC; ++c)
            asm volatile("" : "+a"(Ah[m][c]), "+a"(Al[m][c]));

    // ---- per-chunk B offsets (in-slot u32 index); c<NCA -> x-source
    int boff[NC];
#pragma unroll
    for (int c = 0; c < NC; ++c) {
        int g0 = (c * 8 + w) * 32;
        int gl = (g0 >= KX) ? (g0 - KX) : g0;
        boff[c] = (gl >> 3) * 512 + akg * 512 + arow * 8;
    }
    // ---- bias (hoisted)
    float gbias[4];
#pragma unroll
    for (int g = 0; g < 4; ++g) {
        int rp = gbid * 32 + w * 4 + g;
        gbias[g] = bias[(rp & 3) * H + (rp >> 2)];
    }

    float cs = 0.f;

    for (int t = 0; t < TT; ++t) {
        f32x4 acc[2][4];
#pragma unroll
        for (int m = 0; m < 2; ++m)
#pragma unroll
            for (int ns = 0; ns < 4; ++ns) acc[m][ns] = (f32x4){0.f, 0.f, 0.f, 0.f};

        // ======== phase A: x / ys chunks ========
        if (DEP) {   // ys slot t+1 needs dep (layer0) flag >= t+1
            if (w == 0) {
                bool done = false;
                while (!done) {
                    int d0 = __hip_atomic_load(&depflags[l], __ATOMIC_RELAXED, SCOPE_AGENT);
                    int d1 = __hip_atomic_load(&depflags[l + 64], __ATOMIC_RELAXED, SCOPE_AGENT);
                    done = __all(((d0 < d1) ? d0 : d1) >= t + 1);
                    if (!done) __builtin_amdgcn_s_sleep(1);
                }
            }
            __builtin_amdgcn_sched_barrier(0);
            __syncthreads();
        }
        const u32* xb = xbuf + (size_t)(DEP ? t + 1 : t) * XS;
#pragma unroll
        for (int c = 0; c < NCA; ++c) {
            const u32* bp0 = xb + boff[c];
            u64 raw[4][4];
#pragma unroll
            for (int ns = 0; ns < 4; ++ns) {
                const u32* bp = bp0 + ns * 128;
                *(uint4*)&raw[ns][0] = *(const uint4*)bp;
                *(uint4*)&raw[ns][2] = *(const uint4*)(bp + 4);
            }
#pragma unroll
            for (int ns = 0; ns < 4; ++ns) {
                f16x8 bh, bl;
                unpack8(raw[ns], bh, bl);
#pragma unroll
                for (int m = 0; m < 2; ++m) {
                    acc[m][ns] = MFMA16(Ah[m][c], bh, acc[m][ns], 0, 0, 0);
                    acc[m][ns] = MFMA16(Ah[m][c], bl, acc[m][ns], 0, 0, 0);
                    acc[m][ns] = MFMA16(Al[m][c], bh, acc[m][ns], 0, 0, 0);
                }
            }
        }

        // ======== phase B: h chunks (own flag >= t; trivial at t=0) ========
        if (w == 0) {
            bool done = false;
            while (!done) {
                int o0 = __hip_atomic_load(&ownflags[l], __ATOMIC_RELAXED, SCOPE_AGENT);
                int o1 = __hip_atomic_load(&ownflags[l + 64], __ATOMIC_RELAXED, SCOPE_AGENT);
                done = __all(((o0 < o1) ? o0 : o1) >= t);
                if (!done) __builtin_amdgcn_s_sleep(1);
            }
        }
        __builtin_amdgcn_sched_barrier(0);
        __syncthreads();

        const u32* hb = hbuf + (size_t)t * SLOT;
#pragma unroll
        for (int c = NCA; c < NC; ++c) {
            const u32* bp0 = hb + boff[c];
            u64 raw[4][4];
#pragma unroll
            for (int ns = 0; ns < 4; ++ns) {
                const u32* bp = bp0 + ns * 128;
                *(uint4*)&raw[ns][0] = *(const uint4*)bp;
                *(uint4*)&raw[ns][2] = *(const uint4*)(bp + 4);
            }
#pragma unroll
            for (int ns = 0; ns < 4; ++ns) {
                f16x8 bh, bl;
                unpack8(raw[ns], bh, bl);
#pragma unroll
                for (int m = 0; m < 2; ++m) {
                    acc[m][ns] = MFMA16(Ah[m][c], bh, acc[m][ns], 0, 0, 0);
                    acc[m][ns] = MFMA16(Ah[m][c], bl, acc[m][ns], 0, 0, 0);
                    acc[m][ns] = MFMA16(Al[m][c], bh, acc[m][ns], 0, 0, 0);
                }
            }
        }

        // ---- partial-K reduce via LDS (stride 66: <=2-way conflicts)
#pragma unroll
        for (int m = 0; m < 2; ++m)
#pragma unroll
            for (int ns = 0; ns < 4; ++ns)
#pragma unroll
                for (int r = 0; r < 4; ++r)
                    scr[w][m * 16 + akg * 4 + r][ns * 16 + arow] = acc[m][ns][r];
        __syncthreads();

        // ---- epilogue: thread (unit=w, batch=eb)
        {
            float gg[4];
#pragma unroll
            for (int g = 0; g < 4; ++g) {
                int rl = w * 4 + g;
                float s = 0.f;
#pragma unroll
                for (int ww = 0; ww < 8; ++ww) s += scr[ww][rl][eb];
                gg[g] = s * (1.f / 2048.f) + gbias[g];
            }
            float is = sigm(gg[0]), fs = sigm(gg[1]), gt = tanhf_(gg[2]), os = sigm(gg[3]);
            cs = fs * cs + is * gt;
            float hnew = os * tanhf_(cs);
            hx[w * 72 + eb] = packu(hnew);
        }
        __syncthreads();

        // ---- dense vectorized coherent store: 128 x 16B -> slot t+1
        if (tid < 128) {
            int base = tid * 4;
            u32x4 v;
            v.x = hx[((base + 0) & 7) * 72 + ((base + 0) >> 3)];
            v.y = hx[((base + 1) & 7) * 72 + ((base + 1) >> 3)];
            v.z = hx[((base + 2) & 7) * 72 + ((base + 2) >> 3)];
            v.w = hx[((base + 3) & 7) * 72 + ((base + 3) >> 3)];
            store16_wt(hbuf + (size_t)(t + 1) * SLOT + gbid * 512 + base, v);
        }
        asm volatile("s_waitcnt vmcnt(0)" ::: "memory");
        __syncthreads();   // all stores drained before flag (LOAD-BEARING)
        if (tid == 0)
            __hip_atomic_store(&ownflags[gbid], t + 1, __ATOMIC_RELEASE, SCOPE_AGENT);
    }
}

// ---------------------------------------------------------------------------
// 256 blocks x 512 thr, 1 block/CU. Blocks 0..127: layer 0 (x: xpack, K=1536).
// Blocks 128..255: layer 1 (x: ys slots, K=2048), staggered one step behind.
__global__ __launch_bounds__(512)
__attribute__((amdgpu_waves_per_eu(2, 2)))
void rec_fused(
    const float* __restrict__ Wih0, const float* __restrict__ Whh0, const float* __restrict__ b0,
    const float* __restrict__ Wih1, const float* __restrict__ Whh1, const float* __restrict__ b1,
    const u32* __restrict__ xpack, u32* ys, u32* hs1, int* flags0, int* flags1) {
    __shared__ float scr[8][32][66];
    __shared__ u32 hx[8 * 72];
    const int bid = blockIdx.x;
    if (bid < 128)
        rec_body<6, 2, 512, XSLOT, 0>(Wih0, Whh0, b0, xpack, ys, flags0, nullptr, scr, hx, bid);
    else
        rec_body<8, 4, 1024, SLOT, 1>(Wih1, Whh1, b1, ys, hs1, flags1, flags0, scr, hx, bid - 128);
}

// ---------------------------------------------------------------------------
// out[b][o] = sum_j h[j][b] * Wfc[o][j] + bfc[o]; h from hs1 slot 256
__global__ __launch_bounds__(256) void fc_kernel(
    const u32* __restrict__ hp, const float* __restrict__ Wfc,
    const float* __restrict__ bfc, float* __restrict__ out) {
    const int tid = threadIdx.x;
    const int b = tid & 63;
    const int o = blockIdx.x * 4 + (tid >> 6);
    const float* wr = Wfc + (size_t)o * H;
    float acc = 0.f;
    for (int jb = 0; jb < 128; ++jb) {
        const u64* bp = (const u64*)(hp + (size_t)jb * 512 + b * 8);
        u64 raw[4] = {bp[0], bp[1], bp[2], bp[3]};
        f16x8 vh, vl;
        unpack8(raw, vh, vl);
#pragma unroll
        for (int e = 0; e < 8; ++e) {
            float hv = ((float)vh[e] + (float)vl[e]) * (1.f / 32.f);
            acc += hv * wr[jb * 8 + e];
        }
    }
    out[(size_t)b * 512 + o] = acc + bfc[o];
}

// ---------------------------------------------------------------------------
extern "C" void kernel_launch(void* const* d_in, const int* in_sizes, int n_in,
                              void* d_out, int out_size, void* d_ws, size_t ws_size,
                              hipStream_t stream) {
    const float* x    = (const float*)d_in[0];
    const float* Wih0 = (const float*)d_in[1];
    const float* Whh0 = (const float*)d_in[2];
    const float* b0   = (const float*)d_in[3];
    const float* Wih1 = (const float*)d_in[4];
    const float* Whh1 = (const float*)d_in[5];
    const float* b1   = (const float*)d_in[6];
    const float* Wfc  = (const float*)d_in[7];
    const float* bfc  = (const float*)d_in[8];
    float* out = (float*)d_out;

    // ws (u32): ys 257*SLOT | hs1 257*SLOT | xpack 256*XSLOT | flags0[128] flags1[128]
    char* p = (char*)d_ws;
    u32* ys     = (u32*)p; p += (size_t)257 * SLOT * 4;
    u32* hs1    = (u32*)p; p += (size_t)257 * SLOT * 4;
    u32* xpack  = (u32*)p; p += (size_t)256 * XSLOT * 4;
    int* flags0 = (int*)p; p += 512;
    int* flags1 = (int*)p;

    // zero slot-0 of ys/hs1 + both flag arrays (every launch)
    zero_kernel<<<SLOT / 256, 256, 0, stream>>>(ys, SLOT);
    zero_kernel<<<SLOT / 256, 256, 0, stream>>>(hs1, SLOT);
    zero_kernel<<<1, 256, 0, stream>>>((u32*)flags0, 256);

    xT_kernel<<<TT, 512, 0, stream>>>(x, xpack);

    rec_fused<<<256, 512, 0, stream>>>(
        Wih0, Whh0, b0, Wih1, Whh1, b1, xpack, ys, hs1, flags0, flags1);

    fc_kernel<<<128, 256, 0, stream>>>(hs1 + (size_t)256 * SLOT, Wfc, bfc, out);
}